// Round 1
// baseline (72.301 us; speedup 1.0000x reference)
//
#include <hip/hip_runtime.h>

// Problem constants
#define DD 96
#define HH 96
#define WW 96
#define BN 76                 // BATCH(4) * N_LANDMARKS(19)
#define VOX (DD*HH*WW)        // 884736
#define VOX4 (VOX/4)          // 221184
#define DH4 (DD*HH/4)         // 2304  (voxels4 per d-slice)
#define W4R (WW/4)            // 24    (float4 per w-row)

// ---------------------------------------------------------------------------
// Kernel 1: per-(b,n) separable exp tables + normalization + validity
// grid = 76 blocks, 128 threads (first 96 active for table entries)
// ---------------------------------------------------------------------------
__global__ void tables_kernel(const float* __restrict__ labels,
                              float* __restrict__ ew,
                              float* __restrict__ eh,
                              float* __restrict__ eds,   // ed * inv_s folded
                              float* __restrict__ vflag,
                              float* __restrict__ count) {
    const int bn = blockIdx.x;
    const int i  = threadIdx.x;

    const float lx = labels[bn * 3 + 0];
    const float ly = labels[bn * 3 + 1];
    const float lz = labels[bn * 3 + 2];
    const float x = lx * 95.0f;   // scale = [W-1, H-1, D-1] = 95
    const float y = ly * 95.0f;
    const float z = lz * 95.0f;

    float ewv = 0.0f, ehv = 0.0f, edv = 0.0f;
    if (i < 96) {
        const float fi = (float)i;
        const float dx = fi - x, dy = fi - y, dz = fi - z;
        ewv = __expf(-dx * dx * 0.125f);   // 1/(2*sigma^2) = 1/8
        ehv = __expf(-dy * dy * 0.125f);
        edv = __expf(-dz * dz * 0.125f);
    }

    __shared__ float s0[128], s1[128], s2[128];
    s0[i] = ewv; s1[i] = ehv; s2[i] = edv;
    __syncthreads();
    for (int off = 64; off > 0; off >>= 1) {
        if (i < off) {
            s0[i] += s0[i + off];
            s1[i] += s1[i + off];
            s2[i] += s2[i + off];
        }
        __syncthreads();
    }

    const float s   = s0[0] * s1[0] * s2[0];
    const float inv = (s > 0.0f) ? (1.0f / s) : 1.0f;   // jnp.where(s>0, hm/s, hm)

    if (i < 96) {
        ew [bn * 96 + i] = ewv;
        eh [bn * 96 + i] = ehv;
        eds[bn * 96 + i] = edv * inv;
    }
    if (i == 0) {
        const float v = (lx >= 0.0f) ? 1.0f : 0.0f;   // mask on labels[:,:,0]
        vflag[bn] = v;
        atomicAdd(count, v);
    }
}

// ---------------------------------------------------------------------------
// Kernel 2: main memory-bound pass. |pred - ew*eh*ed/s| masked sum.
// Grid-stride over float4 elements of pred.
// ---------------------------------------------------------------------------
__global__ void __launch_bounds__(256) loss_kernel(
        const float4* __restrict__ pred,
        const float4* __restrict__ ew4,     // 24 float4 per bn
        const float*  __restrict__ eh,
        const float*  __restrict__ eds,
        const float*  __restrict__ vflag,
        float* __restrict__ accum,
        int total4) {
    const int tid    = blockIdx.x * blockDim.x + threadIdx.x;
    const int stride = gridDim.x * blockDim.x;

    float acc = 0.0f;
    for (int i4 = tid; i4 < total4; i4 += stride) {
        const int bn = i4 / VOX4;            // magic-mul
        const int r  = i4 - bn * VOX4;
        const int d  = r / DH4;
        const int r2 = r - d * DH4;
        const int h  = r2 / W4R;
        const int w4 = r2 - h * W4R;

        const float4 p = pred[i4];
        const float4 e = ew4[bn * W4R + w4];
        const float  f = eh[bn * 96 + h] * eds[bn * 96 + d];
        const float  v = vflag[bn];

        const float sa = fabsf(p.x - e.x * f) + fabsf(p.y - e.y * f)
                       + fabsf(p.z - e.z * f) + fabsf(p.w - e.w * f);
        acc += v * sa;
    }

    // wave64 reduce
    for (int off = 32; off > 0; off >>= 1)
        acc += __shfl_down(acc, off, 64);

    __shared__ float wsum[4];
    const int lane = threadIdx.x & 63;
    const int wid  = threadIdx.x >> 6;
    if (lane == 0) wsum[wid] = acc;
    __syncthreads();
    if (threadIdx.x == 0) {
        atomicAdd(accum, wsum[0] + wsum[1] + wsum[2] + wsum[3]);
    }
}

// ---------------------------------------------------------------------------
// Kernel 3: finalize: out = accum / (count + 1e-8)
// ---------------------------------------------------------------------------
__global__ void finalize_kernel(const float* __restrict__ accum,
                                const float* __restrict__ count,
                                float* __restrict__ out) {
    out[0] = accum[0] / (count[0] + 1e-8f);
}

extern "C" void kernel_launch(void* const* d_in, const int* in_sizes, int n_in,
                              void* d_out, int out_size, void* d_ws, size_t ws_size,
                              hipStream_t stream) {
    const float* pred   = (const float*)d_in[0];   // (4,19,96,96,96) f32
    const float* labels = (const float*)d_in[1];   // (4,19,3) f32
    float* out = (float*)d_out;

    char* ws = (char*)d_ws;
    float* accum = (float*)(ws + 0);
    float* count = (float*)(ws + 4);
    float* vflag = (float*)(ws + 16);                 // 76 floats
    float* ew    = (float*)(ws + 512);                // 76*96 floats, 16B aligned
    float* eh    = (float*)(ws + 512 + 29184);        // 76*96 floats
    float* eds   = (float*)(ws + 512 + 2 * 29184);    // 76*96 floats

    // zero accumulator + count each call (ws is NOT re-poisoned between replays)
    hipMemsetAsync(ws, 0, 8, stream);

    tables_kernel<<<BN, 128, 0, stream>>>(labels, ew, eh, eds, vflag, count);

    const int total4 = BN * VOX4;   // 16,809,984
    loss_kernel<<<2048, 256, 0, stream>>>((const float4*)pred, (const float4*)ew,
                                          eh, eds, vflag, accum, total4);

    finalize_kernel<<<1, 1, 0, stream>>>(accum, count, out);
}

// Round 2
// 56.556 us; speedup vs baseline: 1.2784x; 1.2784x over previous
//
#include <hip/hip_runtime.h>

// Problem constants
#define DD 96
#define HH 96
#define WW 96
#define BN 76                 // BATCH(4) * N_LANDMARKS(19)
#define SLICE4 (HH*WW/4)      // 2304 float4 per (bn,d) slice
#define W4R (WW/4)            // 24 float4 per w-row
#define NSLICE (BN*DD)        // 7296 blocks / partials

// ---------------------------------------------------------------------------
// Kernel 1: per-(b,n) separable exp tables + normalization + validity.
// grid = 76 blocks x 128 threads.
// ---------------------------------------------------------------------------
__global__ void tables_kernel(const float* __restrict__ labels,
                              float* __restrict__ ew,
                              float* __restrict__ eh,
                              float* __restrict__ eds,   // ed * inv_s folded
                              float* __restrict__ vflag) {
    const int bn = blockIdx.x;
    const int i  = threadIdx.x;

    const float lx = labels[bn * 3 + 0];
    const float ly = labels[bn * 3 + 1];
    const float lz = labels[bn * 3 + 2];
    const float x = lx * 95.0f;   // scale = [W-1, H-1, D-1] = 95
    const float y = ly * 95.0f;
    const float z = lz * 95.0f;

    float ewv = 0.0f, ehv = 0.0f, edv = 0.0f;
    if (i < 96) {
        const float fi = (float)i;
        const float dx = fi - x, dy = fi - y, dz = fi - z;
        ewv = __expf(-dx * dx * 0.125f);   // 1/(2*sigma^2) = 1/8
        ehv = __expf(-dy * dy * 0.125f);
        edv = __expf(-dz * dz * 0.125f);
    }

    __shared__ float s0[128], s1[128], s2[128];
    s0[i] = ewv; s1[i] = ehv; s2[i] = edv;
    __syncthreads();
    for (int off = 64; off > 0; off >>= 1) {
        if (i < off) {
            s0[i] += s0[i + off];
            s1[i] += s1[i + off];
            s2[i] += s2[i + off];
        }
        __syncthreads();
    }

    const float s   = s0[0] * s1[0] * s2[0];
    const float inv = (s > 0.0f) ? (1.0f / s) : 1.0f;   // jnp.where(s>0, hm/s, hm)

    if (i < 96) {
        ew [bn * 96 + i] = ewv;
        eh [bn * 96 + i] = ehv;
        eds[bn * 96 + i] = edv * inv;
    }
    if (i == 0) {
        vflag[bn] = (lx >= 0.0f) ? 1.0f : 0.0f;   // mask on labels[:,:,0]
    }
}

// ---------------------------------------------------------------------------
// Kernel 2: one block per (bn, d) slice. 256 threads x 9 float4 iters.
// Stages ew (24 float4) and fh[h] = eh[h]*eds[d] in LDS; v applied per-block.
// One partial store per block (no atomics -> deterministic).
// ---------------------------------------------------------------------------
__global__ void __launch_bounds__(256) loss_kernel(
        const float4* __restrict__ pred,
        const float4* __restrict__ ew4,     // [BN][24] float4
        const float*  __restrict__ eh,      // [BN][96]
        const float*  __restrict__ eds,     // [BN][96]
        const float*  __restrict__ vflag,   // [BN]
        float* __restrict__ part) {         // [NSLICE]
    const int bx  = blockIdx.x;
    const int bn  = bx / DD;
    const int d   = bx - bn * DD;
    const int tid = threadIdx.x;

    __shared__ float4 ew_s[W4R];
    __shared__ float  fh_s[HH];

    const float fd = eds[bn * 96 + d];
    if (tid < W4R) ew_s[tid] = ew4[bn * W4R + tid];
    if (tid < HH)  fh_s[tid] = eh[bn * 96 + tid] * fd;
    __syncthreads();

    const float4* p0 = pred + (size_t)bx * SLICE4;
    float acc = 0.0f;
    #pragma unroll
    for (int k = 0; k < 9; ++k) {
        const int t  = tid + k * 256;
        const int h  = t / W4R;
        const int w4 = t - h * W4R;
        const float4 p = p0[t];
        const float4 e = ew_s[w4];
        const float  f = fh_s[h];
        acc += fabsf(p.x - e.x * f) + fabsf(p.y - e.y * f)
             + fabsf(p.z - e.z * f) + fabsf(p.w - e.w * f);
    }
    acc *= vflag[bn];   // block-uniform validity

    // wave64 reduce, then 4 waves -> one store
    for (int off = 32; off > 0; off >>= 1)
        acc += __shfl_down(acc, off, 64);

    __shared__ float wsum[4];
    const int lane = tid & 63;
    const int wid  = tid >> 6;
    if (lane == 0) wsum[wid] = acc;
    __syncthreads();
    if (tid == 0) part[bx] = wsum[0] + wsum[1] + wsum[2] + wsum[3];
}

// ---------------------------------------------------------------------------
// Kernel 3: reduce 7296 partials + vflag count, write final scalar.
// 1 block x 256 threads.
// ---------------------------------------------------------------------------
__global__ void __launch_bounds__(256) finalize_kernel(
        const float* __restrict__ part,
        const float* __restrict__ vflag,
        float* __restrict__ out) {
    const int tid = threadIdx.x;

    float acc = 0.0f;
    for (int i = tid; i < NSLICE; i += 256) acc += part[i];
    float cnt = (tid < BN) ? vflag[tid] : 0.0f;

    for (int off = 32; off > 0; off >>= 1) {
        acc += __shfl_down(acc, off, 64);
        cnt += __shfl_down(cnt, off, 64);
    }
    __shared__ float wsA[4], wsC[4];
    const int lane = tid & 63;
    const int wid  = tid >> 6;
    if (lane == 0) { wsA[wid] = acc; wsC[wid] = cnt; }
    __syncthreads();
    if (tid == 0) {
        const float tot = wsA[0] + wsA[1] + wsA[2] + wsA[3];
        const float c   = wsC[0] + wsC[1] + wsC[2] + wsC[3];
        out[0] = tot / (c + 1e-8f);
    }
}

extern "C" void kernel_launch(void* const* d_in, const int* in_sizes, int n_in,
                              void* d_out, int out_size, void* d_ws, size_t ws_size,
                              hipStream_t stream) {
    const float* pred   = (const float*)d_in[0];   // (4,19,96,96,96) f32
    const float* labels = (const float*)d_in[1];   // (4,19,3) f32
    float* out = (float*)d_out;

    char* ws = (char*)d_ws;
    float* vflag = (float*)(ws + 0);                  // 76 floats
    float* ew    = (float*)(ws + 512);                // 76*96 floats (16B aligned)
    float* eh    = (float*)(ws + 512 + 29184);        // 76*96 floats
    float* eds   = (float*)(ws + 512 + 2 * 29184);    // 76*96 floats
    float* part  = (float*)(ws + 512 + 3 * 29184);    // 7296 floats

    tables_kernel<<<BN, 128, 0, stream>>>(labels, ew, eh, eds, vflag);

    loss_kernel<<<NSLICE, 256, 0, stream>>>((const float4*)pred, (const float4*)ew,
                                            eh, eds, vflag, part);

    finalize_kernel<<<1, 256, 0, stream>>>(part, vflag, out);
}